// Round 5
// baseline (645.946 us; speedup 1.0000x reference)
//
#include <hip/hip_runtime.h>
#include <math.h>

#define NB 2
#define HB 8
#define LB 2048
#define EB 64
#define BITSN 32
#define CLN 128
#define ITERS 10
#define TOPKN 32
#define NEGV -10000000.0f
#define TILES 16
#define PTS 128            // points per kmeans block

typedef unsigned long long u64;
typedef unsigned int u32;

// part layout: part[(nh*TILES + tile)*33 + j]*128 + c   (j=0..31 sums, j=32 cnt)
#define PART_STRIDE (33 * 128)
#define PART_BYTES ((size_t)NB * HB * TILES * PART_STRIDE * 4)   // ~4.125 MB

// ---------------------------------------------------------------------------
// Kernel 1: LSH bits. One wave handles 2 queries; lane = 32*which + b.
// ---------------------------------------------------------------------------
__global__ __launch_bounds__(256) void bits_kernel(const float* __restrict__ q,
                                                   const float* __restrict__ planes,
                                                   u32* __restrict__ bits) {
    int tid = threadIdx.x;
    int wave = tid >> 6;
    int lane = tid & 63;
    int b = lane & 31;
    int which = lane >> 5;
    int qi = blockIdx.x * 8 + wave * 2 + which;   // qi = (n*H + h)*L + l
    int l = qi & (LB - 1);
    int nh = qi / LB;
    int h = nh & (HB - 1);
    int n = nh / HB;
    const float* qrow = q + (((long long)n * LB + l) * HB + h) * EB;
    const float* prow = planes + b * (EB + 1);
    double acc = (double)prow[EB];                 // bias (the ones column)
    #pragma unroll 8
    for (int e = 0; e < EB; ++e) acc += (double)qrow[e] * (double)prow[e];
    unsigned long long m = __ballot(acc > 0.0);
    if (b == 0) {
        bits[qi] = (u32)(which ? (m >> 32) : (m & 0xffffffffULL));
    }
}

// ---------------------------------------------------------------------------
// K-means iteration: 256 blocks (16 nh x 16 tiles), 128 threads (=128 points).
// Each block: recompute cent_k from prev partials (redundant, coalesced L2),
// argmin its points (readlane-cached cents), ballot histogram into LDS,
// coalesced dump to its own partial slice. cent chain materialized (tile 0).
// All integer / exact; argmin = first min; centroid bit: 2*sums >= cnt.
// ---------------------------------------------------------------------------
__global__ __launch_bounds__(128) void kmeans_iter_kernel(const u32* __restrict__ bits,
                                                          const int* __restrict__ part_prev,
                                                          int* __restrict__ part_cur,
                                                          const u32* __restrict__ cent_prev,
                                                          u32* __restrict__ cent_cur,
                                                          int it) {
    __shared__ u32 cent[CLN];
    __shared__ int hist[CLN][33];       // [c][j]: banks (c+j)%32 -> conflict-free
    int tid = threadIdx.x;
    int bid = blockIdx.x;
    int nh = bid >> 4;
    int tile = bid & 15;
    int lane = tid & 63;

    // ---- compute cent_k (c = tid), redundantly per block
    {
        u32 cv;
        if (it == 0) {
            cv = bits[nh * LB + tid * (LB / CLN)];     // init_idx = 16c
        } else {
            int cnt = 0;
            #pragma unroll
            for (int t2 = 0; t2 < TILES; ++t2)
                cnt += part_prev[((nh * TILES + t2) * 33 + 32) * 128 + tid];
            u32 nb = 0u;
            for (int j = 0; j < BITSN; ++j) {
                int s = 0;
                #pragma unroll
                for (int t2 = 0; t2 < TILES; ++t2)
                    s += part_prev[((nh * TILES + t2) * 33 + j) * 128 + tid];
                if (2 * s >= cnt) nb |= (1u << j);
            }
            cv = (cnt > 0) ? nb : cent_prev[nh * CLN + tid];
        }
        cent[tid] = cv;
        if (tile == 0) cent_cur[nh * CLN + tid] = cv;
    }
    // ---- zero hist
    for (int i = tid; i < CLN * 33; i += 128) (&hist[0][0])[i] = 0;
    __syncthreads();

    // ---- my point
    int l = tile * PTS + tid;
    u32 bv = bits[nh * LB + l];

    // per-wave transposed bit masks: lane j<32 holds ballot of bit j
    u64 bT = 0ULL;
    for (int j = 0; j < 32; ++j) {
        u64 t = __ballot((bv >> j) & 1u);
        if (lane == j) bT = t;
    }

    // ---- argmin over 128 cents (readlane-cached, pure VALU)
    u32 clo = cent[lane], chi = cent[lane + 64];
    int best = 99, bc = 0;
    #pragma unroll 16
    for (int c = 0; c < 64; ++c) {
        u32 cc = (u32)__builtin_amdgcn_readlane((int)clo, c);
        int d = __popc(bv ^ cc);
        if (d < best) { best = d; bc = c; }
    }
    #pragma unroll 16
    for (int c = 0; c < 64; ++c) {
        u32 cc = (u32)__builtin_amdgcn_readlane((int)chi, c);
        int d = __popc(bv ^ cc);
        if (d < best) { best = d; bc = 64 + c; }
    }

    // ---- ballot histogram into LDS (2 waves, low contention)
    for (int c = 0; c < CLN; ++c) {
        u64 m = __ballot(bc == c);
        if (m == 0ULL) continue;                   // wave-uniform skip
        if (lane < 32) {
            int v = (int)__popcll(m & bT);
            if (v) atomicAdd(&hist[c][lane], v);
        } else if (lane == 32) {
            atomicAdd(&hist[c][32], (int)__popcll(m));
        }
    }
    __syncthreads();

    // ---- coalesced dump: part_cur[(nh,tile)][j][c] = hist[c][j]
    int base = (nh * TILES + tile) * PART_STRIDE;
    for (int i = tid; i < 33 * 128; i += 128) {
        int j = i >> 7, c = i & 127;
        part_cur[base + i] = hist[c][j];           // LDS read banks (c+j)%32: ok
    }
}

// ---------------------------------------------------------------------------
// Final assignment (reference's 11th distance pass): cent_10 from part_9,
// then argmin -> assign_g.
// ---------------------------------------------------------------------------
__global__ __launch_bounds__(128) void final_assign_kernel(const u32* __restrict__ bits,
                                                           const int* __restrict__ part_prev,
                                                           const u32* __restrict__ cent_prev,
                                                           int* __restrict__ assign_g) {
    __shared__ u32 cent[CLN];
    int tid = threadIdx.x;
    int bid = blockIdx.x;
    int nh = bid >> 4;
    int tile = bid & 15;
    int lane = tid & 63;
    {
        int cnt = 0;
        #pragma unroll
        for (int t2 = 0; t2 < TILES; ++t2)
            cnt += part_prev[((nh * TILES + t2) * 33 + 32) * 128 + tid];
        u32 nb = 0u;
        for (int j = 0; j < BITSN; ++j) {
            int s = 0;
            #pragma unroll
            for (int t2 = 0; t2 < TILES; ++t2)
                s += part_prev[((nh * TILES + t2) * 33 + j) * 128 + tid];
            if (2 * s >= cnt) nb |= (1u << j);
        }
        cent[tid] = (cnt > 0) ? nb : cent_prev[nh * CLN + tid];
    }
    __syncthreads();

    int l = tile * PTS + tid;
    u32 bv = bits[nh * LB + l];
    u32 clo = cent[lane], chi = cent[lane + 64];
    int best = 99, bc = 0;
    #pragma unroll 16
    for (int c = 0; c < 64; ++c) {
        u32 cc = (u32)__builtin_amdgcn_readlane((int)clo, c);
        int d = __popc(bv ^ cc);
        if (d < best) { best = d; bc = c; }
    }
    #pragma unroll 16
    for (int c = 0; c < 64; ++c) {
        u32 cc = (u32)__builtin_amdgcn_readlane((int)chi, c);
        int d = __popc(bv ^ cc);
        if (d < best) { best = d; bc = 64 + c; }
    }
    assign_g[nh * LB + l] = bc;
}

// ---------------------------------------------------------------------------
// Member lists per nh: thread c counts, prefix, emits ascending-l list.
// ---------------------------------------------------------------------------
__global__ __launch_bounds__(128) void list_kernel(const int* __restrict__ assign_g,
                                                   int* __restrict__ cnt_g,
                                                   int* __restrict__ ofs_g,
                                                   int* __restrict__ list_g) {
    __shared__ unsigned char al[LB];
    __shared__ int cshare[CLN];
    __shared__ int ofs[CLN];
    int nh = blockIdx.x;
    int tid = threadIdx.x;        // = c
    for (int l = tid; l < LB; l += 128) al[l] = (unsigned char)assign_g[nh * LB + l];
    __syncthreads();
    int cnt = 0;
    for (int l = 0; l < LB; ++l) cnt += (al[l] == (unsigned char)tid);
    cshare[tid] = cnt;
    __syncthreads();
    if (tid == 0) {
        int run = 0;
        for (int c = 0; c < CLN; ++c) { ofs[c] = run; run += cshare[c]; }
    }
    __syncthreads();
    int p = ofs[tid];
    for (int l = 0; l < LB; ++l)
        if (al[l] == (unsigned char)tid) list_g[nh * LB + p++] = l;
    cnt_g[nh * CLN + tid] = cnt;
    ofs_g[nh * CLN + tid] = ofs[tid];
}

// ---------------------------------------------------------------------------
// Kernel 3a: Qg per (n,h,c) via member list. f64 ascending-l sum, stored f32.
// ---------------------------------------------------------------------------
__global__ __launch_bounds__(64) void qg_kernel(const float* __restrict__ q,
                                                const int* __restrict__ cnt_g,
                                                const int* __restrict__ ofs_g,
                                                const int* __restrict__ list_g,
                                                float* __restrict__ qgf) {
    int bid = blockIdx.x;            // nh*128 + c
    int nh = bid >> 7;
    int h = nh & (HB - 1);
    int n = nh / HB;
    int e = threadIdx.x;
    int cn = cnt_g[bid];
    int o = ofs_g[bid];
    const int* lp = list_g + nh * LB + o;
    double acc = 0.0;
    for (int i = 0; i < cn; ++i) {
        int l = lp[i];
        acc += (double)q[(((long long)n * LB + l) * HB + h) * EB + e];
    }
    double dcn = (double)(cn > 0 ? cn : 1);
    qgf[(long long)bid * EB + e] = (float)(acc / dcn);
}

// ---------------------------------------------------------------------------
// Kernel 3b: scores. Block per (nh, 128-row tile) -> K read exactly once.
// ---------------------------------------------------------------------------
__global__ __launch_bounds__(256) void scores_kernel(const float* __restrict__ kk,
                                                     const float* __restrict__ qgf,
                                                     u32* __restrict__ keys) {
    int bid = blockIdx.x;            // nh*16 + tile
    int nh = bid >> 4;
    int tile = bid & 15;
    int h = nh & (HB - 1);
    int n = nh / HB;
    int w = threadIdx.x >> 6;
    int lane = threadIdx.x & 63;
    int rl = (w & 1) * 64 + lane;    // row within tile
    int l = tile * 128 + rl;
    int cbase = (w >> 1) * 64;       // waves 0,1: c 0-63; waves 2,3: c 64-127

    const float4* kr4 = (const float4*)(kk + (((long long)n * LB + l) * HB + h) * EB);
    float rr[EB];
    #pragma unroll
    for (int i = 0; i < 16; ++i) {
        float4 t4 = kr4[i];
        rr[4 * i] = t4.x; rr[4 * i + 1] = t4.y; rr[4 * i + 2] = t4.z; rr[4 * i + 3] = t4.w;
    }
    const float* qp0 = qgf + ((long long)nh * CLN + cbase) * EB;
    for (int c = 0; c < 64; ++c) {
        const float4* qp = (const float4*)(qp0 + c * EB);   // wave-uniform address
        float acc = 0.f;
        #pragma unroll
        for (int i = 0; i < 16; ++i) {
            float4 qv = qp[i];
            acc = fmaf(qv.x, rr[4 * i], acc);
            acc = fmaf(qv.y, rr[4 * i + 1], acc);
            acc = fmaf(qv.z, rr[4 * i + 2], acc);
            acc = fmaf(qv.w, rr[4 * i + 3], acc);
        }
        u32 u = __float_as_uint(acc);
        u = ((int)u < 0) ? ~u : (u | 0x80000000u);          // monotone f32->u32
        keys[((long long)(nh * CLN + cbase + c)) * LB + l] = u;
    }
}

// ---------------------------------------------------------------------------
// Kernel 3c: top-32 per (n,h,c). One wave; keys packed (key<<32)|(2047-l).
// ---------------------------------------------------------------------------
__global__ __launch_bounds__(64) void topsel_kernel(const u32* __restrict__ keys,
                                                    int* __restrict__ tki) {
    int bid = blockIdx.x;            // nh*128 + c
    int lane = threadIdx.x;
    const uint4* kp4 = (const uint4*)(keys + (long long)bid * LB);
    u64 k[32];
    #pragma unroll
    for (int t = 0; t < 8; ++t) {
        uint4 kv = kp4[lane + 64 * t];
        int l0 = (lane + 64 * t) * 4;
        k[4 * t]     = ((u64)kv.x << 32) | (u32)(2047 - l0);
        k[4 * t + 1] = ((u64)kv.y << 32) | (u32)(2047 - (l0 + 1));
        k[4 * t + 2] = ((u64)kv.z << 32) | (u32)(2047 - (l0 + 2));
        k[4 * t + 3] = ((u64)kv.w << 32) | (u32)(2047 - (l0 + 3));
    }
    u64 m0 = k[0], m1 = k[8], m2 = k[16], m3 = k[24];
    #pragma unroll
    for (int t = 1; t < 8; ++t) {
        if (k[t] > m0) m0 = k[t];
        if (k[8 + t] > m1) m1 = k[8 + t];
        if (k[16 + t] > m2) m2 = k[16 + t];
        if (k[24 + t] > m3) m3 = k[24 + t];
    }
    if (m1 > m0) m0 = m1;
    if (m3 > m2) m2 = m3;
    u64 cur = (m2 > m0) ? m2 : m0;

    for (int r = 0; r < TOPKN; ++r) {
        u64 wk = cur;
        #pragma unroll
        for (int off = 1; off < 64; off <<= 1) {
            u64 o = __shfl_xor(wk, off);
            if (o > wk) wk = o;
        }
        if (lane == 0) tki[bid * TOPKN + r] = 2047 - (int)(wk & 2047u);
        if (wk == cur) {               // unique owner (indices embedded)
            u64 nm = 0ULL;
            #pragma unroll
            for (int t = 0; t < 32; ++t) {
                u64 kt = k[t];
                u64 cand = (kt < wk) ? kt : 0ULL;
                if (cand > nm) nm = cand;
            }
            cur = nm;
        }
    }
}

// ---------------------------------------------------------------------------
// Kernel 4: gather attention. One wave per query (n,h,l).
// ---------------------------------------------------------------------------
__global__ __launch_bounds__(256) void attn_kernel(const float* __restrict__ q,
                                                   const float* __restrict__ kk,
                                                   const float* __restrict__ vv,
                                                   const int* __restrict__ assign_g,
                                                   const int* __restrict__ tki,
                                                   float* __restrict__ out) {
    int tid = threadIdx.x;
    int wave = tid >> 6, lane = tid & 63;
    int qi = blockIdx.x * 4 + wave;   // (nh)*L + l
    int l = qi & (LB - 1);
    int nh = qi / LB;
    int h = nh & (HB - 1);
    int n = nh / HB;
    int c = assign_g[qi];
    const int* krow = tki + (nh * CLN + c) * TOPKN;
    int j = lane & 31, p = lane >> 5;
    int kidx = krow[j];

    const float4* q4 = (const float4*)(q + (((long long)n * LB + l) * HB + h) * EB) + p * 8;
    const float4* k4 = (const float4*)(kk + (((long long)n * LB + kidx) * HB + h) * EB) + p * 8;
    float part = 0.f;
    #pragma unroll
    for (int i = 0; i < 8; ++i) {
        float4 a = q4[i], b = k4[i];
        part += a.x * b.x + a.y * b.y + a.z * b.z + a.w * b.w;
    }
    float qlo = __shfl(part, j);
    float qhi = __shfl(part, j + 32);
    float qk = qlo + qhi;

    bool future = kidx > l;
    float logit = 0.125f * (future ? NEGV : qk);
    float m = logit;
    #pragma unroll
    for (int off = 16; off; off >>= 1) m = fmaxf(m, __shfl_xor(m, off));
    float ex = expf(logit - m);
    float ssum = ex;
    #pragma unroll
    for (int off = 16; off; off >>= 1) ssum += __shfl_xor(ssum, off);
    float a = future ? 0.f : ex / ssum;

    const float* vbase = vv + ((long long)n * LB * HB + h) * EB;  // + ki*H*E + e
    float oacc = 0.f;
    #pragma unroll 4
    for (int jj = 0; jj < TOPKN; ++jj) {
        float aj = __shfl(a, jj);
        int kj = __shfl(kidx, jj);
        if (aj != 0.f)   // wave-uniform
            oacc += aj * vbase[(long long)kj * (HB * EB) + lane];
    }
    out[(((long long)n * LB + l) * HB + h) * EB + lane] = oacc;
}

// ---------------------------------------------------------------------------
extern "C" void kernel_launch(void* const* d_in, const int* in_sizes, int n_in,
                              void* d_out, int out_size, void* d_ws, size_t ws_size,
                              hipStream_t stream) {
    const float* q = (const float*)d_in[0];
    const float* k = (const float*)d_in[1];
    const float* v = (const float*)d_in[2];
    const float* planes = (const float*)d_in[3];
    float* out = (float*)d_out;

    const int NQ = NB * HB * LB;                  // 32768
    char* ws = (char*)d_ws;
    u32* bits     = (u32*)(ws);                    // 128 KB
    int* assign_g = (int*)(ws + 0x20000);          // 128 KB
    int* cnt_g    = (int*)(ws + 0x40000);          // 8 KB
    int* ofs_g    = (int*)(ws + 0x42000);          // 8 KB
    int* list_g   = (int*)(ws + 0x44000);          // 128 KB
    float* qgf    = (float*)(ws + 0x64000);        // 512 KB
    int* tki      = (int*)(ws + 0xE4000);          // 256 KB
    u32* keys     = (u32*)(ws + 0x124000);         // 16 MB (post-cluster)
    // clustering scratch ALIASES the keys region (keys written later):
    int* part0    = (int*)(ws + 0x124000);                  // ~4.125 MB
    int* part1    = (int*)(ws + 0x124000 + PART_BYTES);     // ~4.125 MB
    u32* centb0   = (u32*)(ws + 0x124000 + 2 * PART_BYTES); // 8 KB
    u32* centb1   = (u32*)(ws + 0x124000 + 2 * PART_BYTES + 0x2000);

    bits_kernel<<<NQ / 8, 256, 0, stream>>>(q, planes, bits);

    // 10 k-means iterations, whole-chip (256 blocks each), parity-buffered
    for (int it = 0; it < ITERS; ++it) {
        const int* pp = (it & 1) ? part0 : part1;   // prev parity
        int* pc       = (it & 1) ? part1 : part0;   // cur parity
        const u32* cp = (it & 1) ? centb0 : centb1;
        u32* cc       = (it & 1) ? centb1 : centb0;
        kmeans_iter_kernel<<<NB * HB * TILES, 128, 0, stream>>>(bits, pp, pc, cp, cc, it);
    }
    // after it=9 (odd): cur written = part0? it=9: it&1=1 -> pc=part1, cc=centb1
    final_assign_kernel<<<NB * HB * TILES, 128, 0, stream>>>(bits, part1, centb1, assign_g);
    list_kernel<<<NB * HB, 128, 0, stream>>>(assign_g, cnt_g, ofs_g, list_g);

    qg_kernel<<<NB * HB * CLN, 64, 0, stream>>>(q, cnt_g, ofs_g, list_g, qgf);
    scores_kernel<<<NB * HB * 16, 256, 0, stream>>>(k, qgf, keys);
    topsel_kernel<<<NB * HB * CLN, 64, 0, stream>>>(keys, tki);
    attn_kernel<<<NQ / 4, 256, 0, stream>>>(q, k, v, assign_g, tki, out);
}

// Round 6
// 519.290 us; speedup vs baseline: 1.2439x; 1.2439x over previous
//
#include <hip/hip_runtime.h>
#include <math.h>

#define NB 2
#define HB 8
#define LB 2048
#define EB 64
#define BITSN 32
#define CLN 128
#define ITERS 10
#define TOPKN 32
#define NEGV -10000000.0f
#define TILES 16
#define PTS 128            // points per kmeans block

typedef unsigned long long u64;
typedef unsigned int u32;

// part layout: part[(nh*TILES + tile)*33 + j]*128 + c   (j=0..31 sums, j=32 cnt)
#define PART_STRIDE (33 * 128)
#define PART_BYTES ((size_t)NB * HB * TILES * PART_STRIDE * 4)   // ~4.33 MB

// ---------------------------------------------------------------------------
// Kernel 1: LSH bits. One wave handles 2 queries; lane = 32*which + b.
// ---------------------------------------------------------------------------
__global__ __launch_bounds__(256) void bits_kernel(const float* __restrict__ q,
                                                   const float* __restrict__ planes,
                                                   u32* __restrict__ bits) {
    int tid = threadIdx.x;
    int wave = tid >> 6;
    int lane = tid & 63;
    int b = lane & 31;
    int which = lane >> 5;
    int qi = blockIdx.x * 8 + wave * 2 + which;   // qi = (n*H + h)*L + l
    int l = qi & (LB - 1);
    int nh = qi / LB;
    int h = nh & (HB - 1);
    int n = nh / HB;
    const float* qrow = q + (((long long)n * LB + l) * HB + h) * EB;
    const float* prow = planes + b * (EB + 1);
    double acc = (double)prow[EB];                 // bias (the ones column)
    #pragma unroll 8
    for (int e = 0; e < EB; ++e) acc += (double)qrow[e] * (double)prow[e];
    unsigned long long m = __ballot(acc > 0.0);
    if (b == 0) {
        bits[qi] = (u32)(which ? (m >> 32) : (m & 0xffffffffULL));
    }
}

// ---------------------------------------------------------------------------
// cent_reduce: 16 blocks (one per nh), 128 threads (=clusters). Computes
// cent_it from prev partials (it=0: init from bits). Exact integer math;
// empty-cluster carry from cent_prev.
// ---------------------------------------------------------------------------
__global__ __launch_bounds__(128) void cent_reduce_kernel(const u32* __restrict__ bits,
                                                          const int* __restrict__ part_prev,
                                                          const u32* __restrict__ cent_prev,
                                                          u32* __restrict__ cent_cur,
                                                          int it) {
    int nh = blockIdx.x;
    int c = threadIdx.x;
    if (it == 0) {
        cent_cur[nh * CLN + c] = bits[nh * LB + c * (LB / CLN)];   // init_idx = 16c
        return;
    }
    const int* pp = part_prev + nh * TILES * PART_STRIDE;
    int cnt = 0;
    #pragma unroll
    for (int t2 = 0; t2 < TILES; ++t2) cnt += pp[(t2 * 33 + 32) * 128 + c];
    u32 nb = 0u;
    #pragma unroll
    for (int j = 0; j < BITSN; ++j) {
        int s = 0;
        #pragma unroll
        for (int t2 = 0; t2 < TILES; ++t2) s += pp[(t2 * 33 + j) * 128 + c];
        if (2 * s >= cnt) nb |= (1u << j);
    }
    cent_cur[nh * CLN + c] = (cnt > 0) ? nb : cent_prev[nh * CLN + c];
}

// ---------------------------------------------------------------------------
// kmeans_assign: 256 blocks (16 nh x 16 tiles), 128 threads (=points).
// Reads cent (512B), readlane-argmin, ballot histogram -> LDS, coalesced
// dump to this block's partial slice. Pure VALU + tiny I/O.
// ---------------------------------------------------------------------------
__global__ __launch_bounds__(128) void kmeans_assign_kernel(const u32* __restrict__ bits,
                                                            const u32* __restrict__ cent_g,
                                                            int* __restrict__ part_cur) {
    __shared__ u32 cent[CLN];
    __shared__ int hist[CLN][33];       // [c][j]: banks (c+j)%32 -> conflict-free
    int tid = threadIdx.x;
    int bid = blockIdx.x;
    int nh = bid >> 4;
    int tile = bid & 15;
    int lane = tid & 63;

    cent[tid] = cent_g[nh * CLN + tid];
    for (int i = tid; i < CLN * 33; i += 128) (&hist[0][0])[i] = 0;
    __syncthreads();

    int l = tile * PTS + tid;
    u32 bv = bits[nh * LB + l];

    // per-wave transposed bit masks: lane j<32 holds ballot of bit j
    u64 bT = 0ULL;
    for (int j = 0; j < 32; ++j) {
        u64 t = __ballot((bv >> j) & 1u);
        if (lane == j) bT = t;
    }

    // argmin over 128 cents (readlane-cached, pure VALU; first-min tie rule)
    u32 clo = cent[lane], chi = cent[lane + 64];
    int best = 99, bc = 0;
    #pragma unroll 16
    for (int c = 0; c < 64; ++c) {
        u32 cc = (u32)__builtin_amdgcn_readlane((int)clo, c);
        int d = __popc(bv ^ cc);
        if (d < best) { best = d; bc = c; }
    }
    #pragma unroll 16
    for (int c = 0; c < 64; ++c) {
        u32 cc = (u32)__builtin_amdgcn_readlane((int)chi, c);
        int d = __popc(bv ^ cc);
        if (d < best) { best = d; bc = 64 + c; }
    }

    // ballot histogram into LDS (2 waves, low contention)
    for (int c = 0; c < CLN; ++c) {
        u64 m = __ballot(bc == c);
        if (m == 0ULL) continue;                   // wave-uniform skip
        if (lane < 32) {
            int v = (int)__popcll(m & bT);
            if (v) atomicAdd(&hist[c][lane], v);
        } else if (lane == 32) {
            atomicAdd(&hist[c][32], (int)__popcll(m));
        }
    }
    __syncthreads();

    // coalesced dump: part_cur[(nh,tile)][j][c] = hist[c][j]
    int base = (nh * TILES + tile) * PART_STRIDE;
    for (int i = tid; i < 33 * 128; i += 128) {
        int j = i >> 7, c = i & 127;
        part_cur[base + i] = hist[c][j];
    }
}

// ---------------------------------------------------------------------------
// Final assignment (reference's 11th distance pass) from cent_10.
// ---------------------------------------------------------------------------
__global__ __launch_bounds__(128) void final_assign_kernel(const u32* __restrict__ bits,
                                                           const u32* __restrict__ cent_g,
                                                           int* __restrict__ assign_g) {
    __shared__ u32 cent[CLN];
    int tid = threadIdx.x;
    int bid = blockIdx.x;
    int nh = bid >> 4;
    int tile = bid & 15;
    int lane = tid & 63;
    cent[tid] = cent_g[nh * CLN + tid];
    __syncthreads();

    int l = tile * PTS + tid;
    u32 bv = bits[nh * LB + l];
    u32 clo = cent[lane], chi = cent[lane + 64];
    int best = 99, bc = 0;
    #pragma unroll 16
    for (int c = 0; c < 64; ++c) {
        u32 cc = (u32)__builtin_amdgcn_readlane((int)clo, c);
        int d = __popc(bv ^ cc);
        if (d < best) { best = d; bc = c; }
    }
    #pragma unroll 16
    for (int c = 0; c < 64; ++c) {
        u32 cc = (u32)__builtin_amdgcn_readlane((int)chi, c);
        int d = __popc(bv ^ cc);
        if (d < best) { best = d; bc = 64 + c; }
    }
    assign_g[nh * LB + l] = bc;
}

// ---------------------------------------------------------------------------
// Member lists per nh: ballot-rank, 1024 threads, 2 points each. Emits the
// ascending-l member list deterministically (no serial scans).
// ---------------------------------------------------------------------------
__global__ __launch_bounds__(1024) void list_kernel(const int* __restrict__ assign_g,
                                                    int* __restrict__ cnt_g,
                                                    int* __restrict__ ofs_g,
                                                    int* __restrict__ list_g) {
    __shared__ int cnt[CLN];
    __shared__ int cntw[2][16][CLN];       // (group, wave, cluster)
    __shared__ int ofs[CLN];
    int nh = blockIdx.x;
    int tid = threadIdx.x;
    int w = tid >> 6, lane = tid & 63;
    int l0 = tid, l1 = tid + 1024;
    int bc0 = assign_g[nh * LB + l0];
    int bc1 = assign_g[nh * LB + l1];
    u64 ltmask = (lane == 0) ? 0ULL : (~0ULL >> (64 - lane));

    if (tid < CLN) cnt[tid] = 0;
    for (int i = tid; i < 2 * 16 * CLN; i += 1024) (&cntw[0][0][0])[i] = 0;
    __syncthreads();

    int rank0 = 0, rank1 = 0;
    for (int c = 0; c < CLN; ++c) {
        u64 m0 = __ballot(bc0 == c);
        u64 m1 = __ballot(bc1 == c);
        if ((m0 | m1) == 0ULL) continue;
        if (bc0 == c) rank0 = (int)__popcll(m0 & ltmask);
        if (bc1 == c) rank1 = (int)__popcll(m1 & ltmask);
        if (lane == 0) {
            int p0 = (int)__popcll(m0), p1 = (int)__popcll(m1);
            if (p0) cntw[0][w][c] = p0;
            if (p1) cntw[1][w][c] = p1;
            atomicAdd(&cnt[c], p0 + p1);
        }
    }
    __syncthreads();
    if (tid == 0) {
        int run = 0;
        for (int c = 0; c < CLN; ++c) { ofs[c] = run; run += cnt[c]; }
    }
    __syncthreads();
    if (tid < CLN) {           // absolute bases per (g,w) in ascending-l order
        int c = tid;
        int run = ofs[c];
        #pragma unroll
        for (int g = 0; g < 2; ++g)
            for (int ww = 0; ww < 16; ++ww) {
                int t = cntw[g][ww][c];
                cntw[g][ww][c] = run;
                run += t;
            }
        cnt_g[nh * CLN + c] = cnt[c];
        ofs_g[nh * CLN + c] = ofs[c];
    }
    __syncthreads();
    list_g[nh * LB + cntw[0][w][bc0] + rank0] = l0;
    list_g[nh * LB + cntw[1][w][bc1] + rank1] = l1;
}

// ---------------------------------------------------------------------------
// Kernel 3a: Qg per (n,h,c) via member list. f64 ascending-l sum, stored f32.
// ---------------------------------------------------------------------------
__global__ __launch_bounds__(64) void qg_kernel(const float* __restrict__ q,
                                                const int* __restrict__ cnt_g,
                                                const int* __restrict__ ofs_g,
                                                const int* __restrict__ list_g,
                                                float* __restrict__ qgf) {
    int bid = blockIdx.x;            // nh*128 + c
    int nh = bid >> 7;
    int h = nh & (HB - 1);
    int n = nh / HB;
    int e = threadIdx.x;
    int cn = cnt_g[bid];
    int o = ofs_g[bid];
    const int* lp = list_g + nh * LB + o;
    double acc = 0.0;
    for (int i = 0; i < cn; ++i) {
        int l = lp[i];
        acc += (double)q[(((long long)n * LB + l) * HB + h) * EB + e];
    }
    double dcn = (double)(cn > 0 ? cn : 1);
    qgf[(long long)bid * EB + e] = (float)(acc / dcn);
}

// ---------------------------------------------------------------------------
// Kernel 3b: scores. Block per (nh, 128-row tile) -> K read exactly once.
// ---------------------------------------------------------------------------
__global__ __launch_bounds__(256) void scores_kernel(const float* __restrict__ kk,
                                                     const float* __restrict__ qgf,
                                                     u32* __restrict__ keys) {
    int bid = blockIdx.x;            // nh*16 + tile
    int nh = bid >> 4;
    int tile = bid & 15;
    int h = nh & (HB - 1);
    int n = nh / HB;
    int w = threadIdx.x >> 6;
    int lane = threadIdx.x & 63;
    int rl = (w & 1) * 64 + lane;    // row within tile
    int l = tile * 128 + rl;
    int cbase = (w >> 1) * 64;       // waves 0,1: c 0-63; waves 2,3: c 64-127

    const float4* kr4 = (const float4*)(kk + (((long long)n * LB + l) * HB + h) * EB);
    float rr[EB];
    #pragma unroll
    for (int i = 0; i < 16; ++i) {
        float4 t4 = kr4[i];
        rr[4 * i] = t4.x; rr[4 * i + 1] = t4.y; rr[4 * i + 2] = t4.z; rr[4 * i + 3] = t4.w;
    }
    const float* qp0 = qgf + ((long long)nh * CLN + cbase) * EB;
    for (int c = 0; c < 64; ++c) {
        const float4* qp = (const float4*)(qp0 + c * EB);   // wave-uniform address
        float acc = 0.f;
        #pragma unroll
        for (int i = 0; i < 16; ++i) {
            float4 qv = qp[i];
            acc = fmaf(qv.x, rr[4 * i], acc);
            acc = fmaf(qv.y, rr[4 * i + 1], acc);
            acc = fmaf(qv.z, rr[4 * i + 2], acc);
            acc = fmaf(qv.w, rr[4 * i + 3], acc);
        }
        u32 u = __float_as_uint(acc);
        u = ((int)u < 0) ? ~u : (u | 0x80000000u);          // monotone f32->u32
        keys[((long long)(nh * CLN + cbase + c)) * LB + l] = u;
    }
}

// ---------------------------------------------------------------------------
// Kernel 3c: top-32 per (n,h,c). One wave; keys packed (key<<32)|(2047-l).
// ---------------------------------------------------------------------------
__global__ __launch_bounds__(64) void topsel_kernel(const u32* __restrict__ keys,
                                                    int* __restrict__ tki) {
    int bid = blockIdx.x;            // nh*128 + c
    int lane = threadIdx.x;
    const uint4* kp4 = (const uint4*)(keys + (long long)bid * LB);
    u64 k[32];
    #pragma unroll
    for (int t = 0; t < 8; ++t) {
        uint4 kv = kp4[lane + 64 * t];
        int l0 = (lane + 64 * t) * 4;
        k[4 * t]     = ((u64)kv.x << 32) | (u32)(2047 - l0);
        k[4 * t + 1] = ((u64)kv.y << 32) | (u32)(2047 - (l0 + 1));
        k[4 * t + 2] = ((u64)kv.z << 32) | (u32)(2047 - (l0 + 2));
        k[4 * t + 3] = ((u64)kv.w << 32) | (u32)(2047 - (l0 + 3));
    }
    u64 m0 = k[0], m1 = k[8], m2 = k[16], m3 = k[24];
    #pragma unroll
    for (int t = 1; t < 8; ++t) {
        if (k[t] > m0) m0 = k[t];
        if (k[8 + t] > m1) m1 = k[8 + t];
        if (k[16 + t] > m2) m2 = k[16 + t];
        if (k[24 + t] > m3) m3 = k[24 + t];
    }
    if (m1 > m0) m0 = m1;
    if (m3 > m2) m2 = m3;
    u64 cur = (m2 > m0) ? m2 : m0;

    for (int r = 0; r < TOPKN; ++r) {
        u64 wk = cur;
        #pragma unroll
        for (int off = 1; off < 64; off <<= 1) {
            u64 o = __shfl_xor(wk, off);
            if (o > wk) wk = o;
        }
        if (lane == 0) tki[bid * TOPKN + r] = 2047 - (int)(wk & 2047u);
        if (wk == cur) {               // unique owner (indices embedded)
            u64 nm = 0ULL;
            #pragma unroll
            for (int t = 0; t < 32; ++t) {
                u64 kt = k[t];
                u64 cand = (kt < wk) ? kt : 0ULL;
                if (cand > nm) nm = cand;
            }
            cur = nm;
        }
    }
}

// ---------------------------------------------------------------------------
// Kernel 4: gather attention. One wave per query (n,h,l).
// ---------------------------------------------------------------------------
__global__ __launch_bounds__(256) void attn_kernel(const float* __restrict__ q,
                                                   const float* __restrict__ kk,
                                                   const float* __restrict__ vv,
                                                   const int* __restrict__ assign_g,
                                                   const int* __restrict__ tki,
                                                   float* __restrict__ out) {
    int tid = threadIdx.x;
    int wave = tid >> 6, lane = tid & 63;
    int qi = blockIdx.x * 4 + wave;   // (nh)*L + l
    int l = qi & (LB - 1);
    int nh = qi / LB;
    int h = nh & (HB - 1);
    int n = nh / HB;
    int c = assign_g[qi];
    const int* krow = tki + (nh * CLN + c) * TOPKN;
    int j = lane & 31, p = lane >> 5;
    int kidx = krow[j];

    const float4* q4 = (const float4*)(q + (((long long)n * LB + l) * HB + h) * EB) + p * 8;
    const float4* k4 = (const float4*)(kk + (((long long)n * LB + kidx) * HB + h) * EB) + p * 8;
    float part = 0.f;
    #pragma unroll
    for (int i = 0; i < 8; ++i) {
        float4 a = q4[i], b = k4[i];
        part += a.x * b.x + a.y * b.y + a.z * b.z + a.w * b.w;
    }
    float qlo = __shfl(part, j);
    float qhi = __shfl(part, j + 32);
    float qk = qlo + qhi;

    bool future = kidx > l;
    float logit = 0.125f * (future ? NEGV : qk);
    float m = logit;
    #pragma unroll
    for (int off = 16; off; off >>= 1) m = fmaxf(m, __shfl_xor(m, off));
    float ex = expf(logit - m);
    float ssum = ex;
    #pragma unroll
    for (int off = 16; off; off >>= 1) ssum += __shfl_xor(ssum, off);
    float a = future ? 0.f : ex / ssum;

    const float* vbase = vv + ((long long)n * LB * HB + h) * EB;  // + ki*H*E + e
    float oacc = 0.f;
    #pragma unroll 4
    for (int jj = 0; jj < TOPKN; ++jj) {
        float aj = __shfl(a, jj);
        int kj = __shfl(kidx, jj);
        if (aj != 0.f)   // wave-uniform
            oacc += aj * vbase[(long long)kj * (HB * EB) + lane];
    }
    out[(((long long)n * LB + l) * HB + h) * EB + lane] = oacc;
}

// ---------------------------------------------------------------------------
extern "C" void kernel_launch(void* const* d_in, const int* in_sizes, int n_in,
                              void* d_out, int out_size, void* d_ws, size_t ws_size,
                              hipStream_t stream) {
    const float* q = (const float*)d_in[0];
    const float* k = (const float*)d_in[1];
    const float* v = (const float*)d_in[2];
    const float* planes = (const float*)d_in[3];
    float* out = (float*)d_out;

    const int NQ = NB * HB * LB;                  // 32768
    char* ws = (char*)d_ws;
    u32* bits     = (u32*)(ws);                    // 128 KB
    int* assign_g = (int*)(ws + 0x20000);          // 128 KB
    int* cnt_g    = (int*)(ws + 0x40000);          // 8 KB
    int* ofs_g    = (int*)(ws + 0x42000);          // 8 KB
    int* list_g   = (int*)(ws + 0x44000);          // 128 KB
    float* qgf    = (float*)(ws + 0x64000);        // 512 KB
    int* tki      = (int*)(ws + 0xE4000);          // 256 KB
    u32* keys     = (u32*)(ws + 0x124000);         // 16 MB (post-cluster)
    // clustering scratch ALIASES the keys region (keys written later):
    int* parts[2];
    parts[0] = (int*)(ws + 0x124000);
    parts[1] = (int*)(ws + 0x124000 + PART_BYTES);
    u32* cents[2];
    cents[0] = (u32*)(ws + 0x124000 + 2 * PART_BYTES);
    cents[1] = (u32*)(ws + 0x124000 + 2 * PART_BYTES + 0x2000);

    bits_kernel<<<NQ / 8, 256, 0, stream>>>(q, planes, bits);

    // 10 k-means iterations: cent_reduce (16 blocks) + assign (256 blocks)
    for (int it = 0; it < ITERS; ++it) {
        const int* pp = parts[(it + 1) & 1];       // written by iteration it-1
        const u32* cp = cents[(it + 1) & 1];
        u32* cc       = cents[it & 1];
        cent_reduce_kernel<<<NB * HB, 128, 0, stream>>>(bits, pp, cp, cc, it);
        kmeans_assign_kernel<<<NB * HB * TILES, 128, 0, stream>>>(bits, cc, parts[it & 1]);
    }
    // cent_10 from part_9 (parity 1), carry from cent_9 (parity 1) -> cents[0]
    cent_reduce_kernel<<<NB * HB, 128, 0, stream>>>(bits, parts[1], cents[1], cents[0], 10);
    final_assign_kernel<<<NB * HB * TILES, 128, 0, stream>>>(bits, cents[0], assign_g);
    list_kernel<<<NB * HB, 1024, 0, stream>>>(assign_g, cnt_g, ofs_g, list_g);

    qg_kernel<<<NB * HB * CLN, 64, 0, stream>>>(q, cnt_g, ofs_g, list_g, qgf);
    scores_kernel<<<NB * HB * 16, 256, 0, stream>>>(k, qgf, keys);
    topsel_kernel<<<NB * HB * CLN, 64, 0, stream>>>(keys, tki);
    attn_kernel<<<NQ / 4, 256, 0, stream>>>(q, k, v, assign_g, tki, out);
}

// Round 7
// 308.493 us; speedup vs baseline: 2.0939x; 1.6833x over previous
//
#include <hip/hip_runtime.h>
#include <math.h>

#define NB 2
#define HB 8
#define LB 2048
#define EB 64
#define BITSN 32
#define CLN 128
#define ITERS 10
#define TOPKN 32
#define NEGV -10000000.0f

typedef unsigned long long u64;
typedef unsigned int u32;

// reduced part layout per iteration: part[nh][j][c], j=0..31 sums, j=32 cnt
#define PART_NH (33 * 128)                          // 4224 dwords per nh
#define PART_ITER (NB * HB * PART_NH)               // 67584 dwords per iteration
#define PART_TOTAL (ITERS * PART_ITER)              // 675840 dwords (~2.6 MB)

// ---------------------------------------------------------------------------
// Kernel 1: LSH bits. One wave handles 2 queries; lane = 32*which + b.
// ---------------------------------------------------------------------------
__global__ __launch_bounds__(256) void bits_kernel(const float* __restrict__ q,
                                                   const float* __restrict__ planes,
                                                   u32* __restrict__ bits) {
    int tid = threadIdx.x;
    int wave = tid >> 6;
    int lane = tid & 63;
    int b = lane & 31;
    int which = lane >> 5;
    int qi = blockIdx.x * 8 + wave * 2 + which;   // qi = (n*H + h)*L + l
    int l = qi & (LB - 1);
    int nh = qi / LB;
    int h = nh & (HB - 1);
    int n = nh / HB;
    const float* qrow = q + (((long long)n * LB + l) * HB + h) * EB;
    const float* prow = planes + b * (EB + 1);
    double acc = (double)prow[EB];                 // bias (the ones column)
    #pragma unroll 8
    for (int e = 0; e < EB; ++e) acc += (double)qrow[e] * (double)prow[e];
    unsigned long long m = __ballot(acc > 0.0);
    if (b == 0) {
        bits[qi] = (u32)(which ? (m >> 32) : (m & 0xffffffffULL));
    }
}

// ---------------------------------------------------------------------------
// Zero the k-means partial buffers (once per launch; atomics accumulate).
// ---------------------------------------------------------------------------
__global__ __launch_bounds__(256) void zero_kernel(int* __restrict__ p, int n) {
    int i = blockIdx.x * 256 + threadIdx.x;
    if (i < n) p[i] = 0;
}

// ---------------------------------------------------------------------------
// Fused k-means iteration: 128 blocks (16 nh x 8 tiles of 256 points),
// 256 threads (= points). Per block:
//   (1) cent_it from part[it-1] (already reduced; 33 coalesced loads/thread)
//       with empty-cluster carry from the materialized cent chain,
//   (2) readlane-cached pure-VALU argmin (first-min tie rule),
//   (3) per-set-bit LDS atomic histogram (low contention: ~2 pts/cluster),
//   (4) global-atomic dump into part[it] (integer adds -> deterministic).
// ---------------------------------------------------------------------------
__global__ __launch_bounds__(256) void kmeans_iter_kernel(const u32* __restrict__ bits,
                                                          const int* __restrict__ part_prev,
                                                          int* __restrict__ part_cur,
                                                          const u32* __restrict__ cent_prev_g,
                                                          u32* __restrict__ cent_cur_g,
                                                          int it) {
    __shared__ u32 cent[CLN];
    __shared__ int hist[PART_NH];        // [j*128+c]
    int tid = threadIdx.x;
    int bid = blockIdx.x;
    int nh = bid >> 3;
    int tile = bid & 7;
    int lane = tid & 63;

    // ---- (1) centroids for this iteration (redundant per block, cheap)
    if (tid < CLN) {
        int c = tid;
        u32 cv;
        if (it == 0) {
            cv = bits[nh * LB + c * (LB / CLN)];        // init_idx = 16c
        } else {
            const int* pp = part_prev + nh * PART_NH;
            int cnt = pp[32 * 128 + c];
            u32 nb = 0u;
            #pragma unroll
            for (int j = 0; j < BITSN; ++j) {
                int s = pp[j * 128 + c];
                if (2 * s >= cnt) nb |= (1u << j);
            }
            cv = (cnt > 0) ? nb : cent_prev_g[nh * CLN + c];
        }
        cent[c] = cv;
        if (tile == 0) cent_cur_g[nh * CLN + c] = cv;   // materialize chain
    }
    for (int i = tid; i < PART_NH; i += 256) hist[i] = 0;
    __syncthreads();

    // ---- my point
    int l = tile * 256 + tid;
    u32 bv = bits[nh * LB + l];

    // ---- (2) argmin over 128 cents (readlane-cached, pure VALU)
    u32 clo = cent[lane], chi = cent[lane + 64];
    int best = 99, bc = 0;
    #pragma unroll 16
    for (int c = 0; c < 64; ++c) {
        u32 cc = (u32)__builtin_amdgcn_readlane((int)clo, c);
        int d = __popc(bv ^ cc);
        if (d < best) { best = d; bc = c; }
    }
    #pragma unroll 16
    for (int c = 0; c < 64; ++c) {
        u32 cc = (u32)__builtin_amdgcn_readlane((int)chi, c);
        int d = __popc(bv ^ cc);
        if (d < best) { best = d; bc = 64 + c; }
    }

    // ---- (3) per-set-bit LDS histogram (exact integer adds)
    atomicAdd(&hist[32 * 128 + bc], 1);
    u32 bb = bv;
    while (bb) {
        int j = __ffs(bb) - 1;
        atomicAdd(&hist[j * 128 + bc], 1);
        bb &= bb - 1;
    }
    __syncthreads();

    // ---- (4) dump to reduced global partials (coalesced atomic adds)
    int base = nh * PART_NH;
    for (int i = tid; i < PART_NH; i += 256) {
        int v = hist[i];
        if (v) atomicAdd(&part_cur[base + i], v);
    }
}

// ---------------------------------------------------------------------------
// Final assignment (reference's 11th distance pass): cent_10 from part[9]
// (carry cent_9), then argmin -> assign_g.
// ---------------------------------------------------------------------------
__global__ __launch_bounds__(256) void final_assign_kernel(const u32* __restrict__ bits,
                                                           const int* __restrict__ part_prev,
                                                           const u32* __restrict__ cent_prev_g,
                                                           int* __restrict__ assign_g) {
    __shared__ u32 cent[CLN];
    int tid = threadIdx.x;
    int bid = blockIdx.x;
    int nh = bid >> 3;
    int tile = bid & 7;
    int lane = tid & 63;
    if (tid < CLN) {
        int c = tid;
        const int* pp = part_prev + nh * PART_NH;
        int cnt = pp[32 * 128 + c];
        u32 nb = 0u;
        #pragma unroll
        for (int j = 0; j < BITSN; ++j) {
            int s = pp[j * 128 + c];
            if (2 * s >= cnt) nb |= (1u << j);
        }
        cent[c] = (cnt > 0) ? nb : cent_prev_g[nh * CLN + c];
    }
    __syncthreads();

    int l = tile * 256 + tid;
    u32 bv = bits[nh * LB + l];
    u32 clo = cent[lane], chi = cent[lane + 64];
    int best = 99, bc = 0;
    #pragma unroll 16
    for (int c = 0; c < 64; ++c) {
        u32 cc = (u32)__builtin_amdgcn_readlane((int)clo, c);
        int d = __popc(bv ^ cc);
        if (d < best) { best = d; bc = c; }
    }
    #pragma unroll 16
    for (int c = 0; c < 64; ++c) {
        u32 cc = (u32)__builtin_amdgcn_readlane((int)chi, c);
        int d = __popc(bv ^ cc);
        if (d < best) { best = d; bc = 64 + c; }
    }
    assign_g[nh * LB + l] = bc;
}

// ---------------------------------------------------------------------------
// Member lists per nh: ballot-rank, 1024 threads, 2 points each. Emits the
// ascending-l member list deterministically.
// ---------------------------------------------------------------------------
__global__ __launch_bounds__(1024) void list_kernel(const int* __restrict__ assign_g,
                                                    int* __restrict__ cnt_g,
                                                    int* __restrict__ ofs_g,
                                                    int* __restrict__ list_g) {
    __shared__ int cnt[CLN];
    __shared__ int cntw[2][16][CLN];       // (group, wave, cluster)
    __shared__ int ofs[CLN];
    int nh = blockIdx.x;
    int tid = threadIdx.x;
    int w = tid >> 6, lane = tid & 63;
    int l0 = tid, l1 = tid + 1024;
    int bc0 = assign_g[nh * LB + l0];
    int bc1 = assign_g[nh * LB + l1];
    u64 ltmask = (lane == 0) ? 0ULL : (~0ULL >> (64 - lane));

    if (tid < CLN) cnt[tid] = 0;
    for (int i = tid; i < 2 * 16 * CLN; i += 1024) (&cntw[0][0][0])[i] = 0;
    __syncthreads();

    int rank0 = 0, rank1 = 0;
    for (int c = 0; c < CLN; ++c) {
        u64 m0 = __ballot(bc0 == c);
        u64 m1 = __ballot(bc1 == c);
        if ((m0 | m1) == 0ULL) continue;
        if (bc0 == c) rank0 = (int)__popcll(m0 & ltmask);
        if (bc1 == c) rank1 = (int)__popcll(m1 & ltmask);
        if (lane == 0) {
            int p0 = (int)__popcll(m0), p1 = (int)__popcll(m1);
            if (p0) cntw[0][w][c] = p0;
            if (p1) cntw[1][w][c] = p1;
            atomicAdd(&cnt[c], p0 + p1);
        }
    }
    __syncthreads();
    if (tid == 0) {
        int run = 0;
        for (int c = 0; c < CLN; ++c) { ofs[c] = run; run += cnt[c]; }
    }
    __syncthreads();
    if (tid < CLN) {           // absolute bases per (g,w) in ascending-l order
        int c = tid;
        int run = ofs[c];
        #pragma unroll
        for (int g = 0; g < 2; ++g)
            for (int ww = 0; ww < 16; ++ww) {
                int t = cntw[g][ww][c];
                cntw[g][ww][c] = run;
                run += t;
            }
        cnt_g[nh * CLN + c] = cnt[c];
        ofs_g[nh * CLN + c] = ofs[c];
    }
    __syncthreads();
    list_g[nh * LB + cntw[0][w][bc0] + rank0] = l0;
    list_g[nh * LB + cntw[1][w][bc1] + rank1] = l1;
}

// ---------------------------------------------------------------------------
// Kernel 3a: Qg per (n,h,c) via member list. f64 ascending-l sum, stored f32.
// ---------------------------------------------------------------------------
__global__ __launch_bounds__(64) void qg_kernel(const float* __restrict__ q,
                                                const int* __restrict__ cnt_g,
                                                const int* __restrict__ ofs_g,
                                                const int* __restrict__ list_g,
                                                float* __restrict__ qgf) {
    int bid = blockIdx.x;            // nh*128 + c
    int nh = bid >> 7;
    int h = nh & (HB - 1);
    int n = nh / HB;
    int e = threadIdx.x;
    int cn = cnt_g[bid];
    int o = ofs_g[bid];
    const int* lp = list_g + nh * LB + o;
    double acc = 0.0;
    for (int i = 0; i < cn; ++i) {
        int l = lp[i];
        acc += (double)q[(((long long)n * LB + l) * HB + h) * EB + e];
    }
    double dcn = (double)(cn > 0 ? cn : 1);
    qgf[(long long)bid * EB + e] = (float)(acc / dcn);
}

// ---------------------------------------------------------------------------
// Kernel 3b: scores. Block per (nh, 128-row tile) -> K read exactly once.
// ---------------------------------------------------------------------------
__global__ __launch_bounds__(256) void scores_kernel(const float* __restrict__ kk,
                                                     const float* __restrict__ qgf,
                                                     u32* __restrict__ keys) {
    int bid = blockIdx.x;            // nh*16 + tile
    int nh = bid >> 4;
    int tile = bid & 15;
    int h = nh & (HB - 1);
    int n = nh / HB;
    int w = threadIdx.x >> 6;
    int lane = threadIdx.x & 63;
    int rl = (w & 1) * 64 + lane;    // row within tile
    int l = tile * 128 + rl;
    int cbase = (w >> 1) * 64;       // waves 0,1: c 0-63; waves 2,3: c 64-127

    const float4* kr4 = (const float4*)(kk + (((long long)n * LB + l) * HB + h) * EB);
    float rr[EB];
    #pragma unroll
    for (int i = 0; i < 16; ++i) {
        float4 t4 = kr4[i];
        rr[4 * i] = t4.x; rr[4 * i + 1] = t4.y; rr[4 * i + 2] = t4.z; rr[4 * i + 3] = t4.w;
    }
    const float* qp0 = qgf + ((long long)nh * CLN + cbase) * EB;
    for (int c = 0; c < 64; ++c) {
        const float4* qp = (const float4*)(qp0 + c * EB);   // wave-uniform address
        float acc = 0.f;
        #pragma unroll
        for (int i = 0; i < 16; ++i) {
            float4 qv = qp[i];
            acc = fmaf(qv.x, rr[4 * i], acc);
            acc = fmaf(qv.y, rr[4 * i + 1], acc);
            acc = fmaf(qv.z, rr[4 * i + 2], acc);
            acc = fmaf(qv.w, rr[4 * i + 3], acc);
        }
        u32 u = __float_as_uint(acc);
        u = ((int)u < 0) ? ~u : (u | 0x80000000u);          // monotone f32->u32
        keys[((long long)(nh * CLN + cbase + c)) * LB + l] = u;
    }
}

// ---------------------------------------------------------------------------
// Kernel 3c: top-32 per (n,h,c). One wave; keys packed (key<<32)|(2047-l).
// ---------------------------------------------------------------------------
__global__ __launch_bounds__(64) void topsel_kernel(const u32* __restrict__ keys,
                                                    int* __restrict__ tki) {
    int bid = blockIdx.x;            // nh*128 + c
    int lane = threadIdx.x;
    const uint4* kp4 = (const uint4*)(keys + (long long)bid * LB);
    u64 k[32];
    #pragma unroll
    for (int t = 0; t < 8; ++t) {
        uint4 kv = kp4[lane + 64 * t];
        int l0 = (lane + 64 * t) * 4;
        k[4 * t]     = ((u64)kv.x << 32) | (u32)(2047 - l0);
        k[4 * t + 1] = ((u64)kv.y << 32) | (u32)(2047 - (l0 + 1));
        k[4 * t + 2] = ((u64)kv.z << 32) | (u32)(2047 - (l0 + 2));
        k[4 * t + 3] = ((u64)kv.w << 32) | (u32)(2047 - (l0 + 3));
    }
    u64 m0 = k[0], m1 = k[8], m2 = k[16], m3 = k[24];
    #pragma unroll
    for (int t = 1; t < 8; ++t) {
        if (k[t] > m0) m0 = k[t];
        if (k[8 + t] > m1) m1 = k[8 + t];
        if (k[16 + t] > m2) m2 = k[16 + t];
        if (k[24 + t] > m3) m3 = k[24 + t];
    }
    if (m1 > m0) m0 = m1;
    if (m3 > m2) m2 = m3;
    u64 cur = (m2 > m0) ? m2 : m0;

    for (int r = 0; r < TOPKN; ++r) {
        u64 wk = cur;
        #pragma unroll
        for (int off = 1; off < 64; off <<= 1) {
            u64 o = __shfl_xor(wk, off);
            if (o > wk) wk = o;
        }
        if (lane == 0) tki[bid * TOPKN + r] = 2047 - (int)(wk & 2047u);
        if (wk == cur) {               // unique owner (indices embedded)
            u64 nm = 0ULL;
            #pragma unroll
            for (int t = 0; t < 32; ++t) {
                u64 kt = k[t];
                u64 cand = (kt < wk) ? kt : 0ULL;
                if (cand > nm) nm = cand;
            }
            cur = nm;
        }
    }
}

// ---------------------------------------------------------------------------
// Kernel 4: gather attention. One wave per query (n,h,l). V columns are
// preloaded into registers (32 independent coalesced loads in flight before
// the QK/softmax dependency chain).
// ---------------------------------------------------------------------------
__global__ __launch_bounds__(256) void attn_kernel(const float* __restrict__ q,
                                                   const float* __restrict__ kk,
                                                   const float* __restrict__ vv,
                                                   const int* __restrict__ assign_g,
                                                   const int* __restrict__ tki,
                                                   float* __restrict__ out) {
    int tid = threadIdx.x;
    int wave = tid >> 6, lane = tid & 63;
    int qi = blockIdx.x * 4 + wave;   // (nh)*L + l
    int l = qi & (LB - 1);
    int nh = qi / LB;
    int h = nh & (HB - 1);
    int n = nh / HB;
    int c = assign_g[qi];
    const int* krow = tki + (nh * CLN + c) * TOPKN;
    int j = lane & 31, p = lane >> 5;
    int kidx = krow[j];

    // preload V: vreg[jj] = V[kj(jj)][lane]  (coalesced 256B rows, high ILP)
    const float* vbase = vv + ((long long)n * LB * HB + h) * EB;  // + ki*H*E + e
    float vreg[TOPKN];
    #pragma unroll
    for (int jj = 0; jj < TOPKN; ++jj) {
        int kj = __shfl(kidx, jj);
        vreg[jj] = vbase[(long long)kj * (HB * EB) + lane];
    }

    const float4* q4 = (const float4*)(q + (((long long)n * LB + l) * HB + h) * EB) + p * 8;
    const float4* k4 = (const float4*)(kk + (((long long)n * LB + kidx) * HB + h) * EB) + p * 8;
    float part = 0.f;
    #pragma unroll
    for (int i = 0; i < 8; ++i) {
        float4 a = q4[i], b = k4[i];
        part += a.x * b.x + a.y * b.y + a.z * b.z + a.w * b.w;
    }
    float qlo = __shfl(part, j);
    float qhi = __shfl(part, j + 32);
    float qk = qlo + qhi;

    bool future = kidx > l;
    float logit = 0.125f * (future ? NEGV : qk);
    float m = logit;
    #pragma unroll
    for (int off = 16; off; off >>= 1) m = fmaxf(m, __shfl_xor(m, off));
    float ex = expf(logit - m);
    float ssum = ex;
    #pragma unroll
    for (int off = 16; off; off >>= 1) ssum += __shfl_xor(ssum, off);
    float a = future ? 0.f : ex / ssum;   // a==0 exactly for masked keys

    float oacc = 0.f;
    #pragma unroll
    for (int jj = 0; jj < TOPKN; ++jj) {
        float aj = __shfl(a, jj);
        oacc = fmaf(aj, vreg[jj], oacc);  // aj==0 contributes exactly 0
    }
    out[(((long long)n * LB + l) * HB + h) * EB + lane] = oacc;
}

// ---------------------------------------------------------------------------
extern "C" void kernel_launch(void* const* d_in, const int* in_sizes, int n_in,
                              void* d_out, int out_size, void* d_ws, size_t ws_size,
                              hipStream_t stream) {
    const float* q = (const float*)d_in[0];
    const float* k = (const float*)d_in[1];
    const float* v = (const float*)d_in[2];
    const float* planes = (const float*)d_in[3];
    float* out = (float*)d_out;

    const int NQ = NB * HB * LB;                  // 32768
    char* ws = (char*)d_ws;
    u32* bits     = (u32*)(ws);                    // 128 KB
    int* assign_g = (int*)(ws + 0x20000);          // 128 KB
    int* cnt_g    = (int*)(ws + 0x40000);          // 8 KB
    int* ofs_g    = (int*)(ws + 0x42000);          // 8 KB
    int* list_g   = (int*)(ws + 0x44000);          // 128 KB
    float* qgf    = (float*)(ws + 0x64000);        // 512 KB
    int* tki      = (int*)(ws + 0xE4000);          // 256 KB
    u32* keys     = (u32*)(ws + 0x124000);         // 16 MB (written post-cluster)
    // clustering scratch ALIASES the keys region (dead once scores runs):
    int* part_all = (int*)(ws + 0x124000);                 // 2.6 MB (10 iters)
    u32* centg0   = (u32*)(ws + 0x124000 + 0x300000);      // 8 KB
    u32* centg1   = (u32*)(ws + 0x124000 + 0x302000);      // 8 KB

    bits_kernel<<<NQ / 8, 256, 0, stream>>>(q, planes, bits);
    zero_kernel<<<(PART_TOTAL + 255) / 256, 256, 0, stream>>>(part_all, PART_TOTAL);

    // 10 fused k-means iterations (serial depth = 10)
    for (int it = 0; it < ITERS; ++it) {
        const int* pp = part_all + (it == 0 ? 0 : (it - 1)) * PART_ITER;
        int* pc       = part_all + it * PART_ITER;
        const u32* cprev = (it & 1) ? centg0 : centg1;   // cent_{it-1}
        u32* ccur        = (it & 1) ? centg1 : centg0;   // cent_it
        kmeans_iter_kernel<<<NB * HB * 8, 256, 0, stream>>>(bits, pp, pc, cprev, ccur, it);
    }
    // cent_10 from part[9], carry cent_9 (parity 1)
    final_assign_kernel<<<NB * HB * 8, 256, 0, stream>>>(
        bits, part_all + 9 * PART_ITER, centg1, assign_g);
    list_kernel<<<NB * HB, 1024, 0, stream>>>(assign_g, cnt_g, ofs_g, list_g);

    qg_kernel<<<NB * HB * CLN, 64, 0, stream>>>(q, cnt_g, ofs_g, list_g, qgf);
    scores_kernel<<<NB * HB * 16, 256, 0, stream>>>(k, qgf, keys);
    topsel_kernel<<<NB * HB * CLN, 64, 0, stream>>>(keys, tki);
    attn_kernel<<<NQ / 4, 256, 0, stream>>>(q, k, v, assign_g, tki, out);
}